// Round 10
// baseline (79.949 us; speedup 1.0000x reference)
//
#include <hip/hip_runtime.h>
#include <math.h>

#define LSEQ 512
#define EDIM 256
#define PDIM 2048
#define BM   128
#define BK   32
#define NT   16      // K-steps = LSEQ/BK

typedef _Float16 f16x8 __attribute__((ext_vector_type(8)));
typedef _Float16 f16x2 __attribute__((ext_vector_type(2)));
typedef float    f32x4 __attribute__((ext_vector_type(4)));

#if __has_builtin(__builtin_amdgcn_exp2f)
#define EXP2F(x) __builtin_amdgcn_exp2f(x)
#else
#define EXP2F(x) __expf((x) * 0.6931471805599453f)
#endif

__device__ inline f16x2 pk2(float a, float b) {
#if __has_builtin(__builtin_amdgcn_cvt_pkrtz)
    return __builtin_bit_cast(f16x2, __builtin_amdgcn_cvt_pkrtz(a, b));
#else
    f16x2 r; r[0] = (_Float16)a; r[1] = (_Float16)b; return r;
#endif
}

__device__ inline float hw_sin(float ang) {
#if __has_builtin(__builtin_amdgcn_sinf)
    float rev = ang * 0.15915494309189535f;
    return __builtin_amdgcn_sinf(rev - floorf(rev));
#else
    return sinf(ang);
#endif
}
__device__ inline float hw_cos(float ang) {
#if __has_builtin(__builtin_amdgcn_cosf)
    float rev = ang * 0.15915494309189535f;
    return __builtin_amdgcn_cosf(rev - floorf(rev));
#else
    return cosf(ang);
#endif
}

// Conflict-balanced interleaved tile layout (fp16 element offset) for a
// [rows][32] fp16 tile stored as 128B row-pairs. r = row, g = k-group (0..3).
__device__ __host__ inline int tile_off(int r, int g) {
    return ((r >> 1) << 6) + ((r & 1) << 5) + (((g ^ ((r >> 1) & 3)) & 3) << 3);
}

__device__ inline void g2lds16(const void* g, void* l) {
    __builtin_amdgcn_global_load_lds(
        (const __attribute__((address_space(1))) void*)g,
        (__attribute__((address_space(3))) void*)l, 16, 0, 0);
}

// ---- fused precompute: one block per (b, k-step) baset chunk ---------------
// Also writes params[b, l] = {-0.5/w^2 * log2e, log2(amp)} for its 32 l's.
__global__ __launch_bounds__(256) void precompute_all(
    const int*   __restrict__ bs,      // (B, L)
    const float* __restrict__ ls,      // (256, 3)
    const float* __restrict__ emb,     // (256, E)
    float2*      __restrict__ params,  // (B, L)
    _Float16*    __restrict__ baset) { // (B*NT) chunks of 16 KB
    const int b   = blockIdx.x >> 4;
    const int t   = blockIdx.x & 15;
    const int tid = threadIdx.x;       // = e (0..255)

    __shared__ int sByte[BK];
    if (tid < BK) {
        const int l    = t * BK + tid;
        const int byte = bs[b * LSEQ + l];
        sByte[tid] = byte;
        const float l1  = ls[byte * 3 + 1];
        const float l2  = ls[byte * 3 + 2];
        const float wdt = fabsf(l1) * 0.02f + 1e-5f;
        const float amp = 1.0f / (1.0f + __expf(-l2));
        params[b * LSEQ + l] = make_float2(-0.72134752f / (wdt * wdt),  // -0.5*log2e/w^2
                                           __log2f(amp));
    }
    __syncthreads();

    // PE dim e: pair index e>>1, phase e&1 (0=sin, 1=cos)
    const float div = __expf((float)(tid >> 1) * (-2.0f * 9.210340372f / 256.0f));
    _Float16* chunk = baset + ((size_t)blockIdx.x << 13);
#pragma unroll
    for (int g = 0; g < 4; ++g) {
        f16x8 v;
#pragma unroll
        for (int j = 0; j < 8; ++j) {
            const int lj  = g * 8 + j;
            const float ang = (float)(t * BK + lj) * div;
            const float pev = (tid & 1) ? hw_cos(ang) : hw_sin(ang);
            v[j] = (_Float16)(emb[sByte[lj] * EDIM + tid] + pev);
        }
        *(f16x8*)&chunk[tile_off(tid, g)] = v;
    }
}

// ----------------------------- MFMA field kernel ----------------------------
// 256 thr (4 waves, 2x2). Block tile 128p x 128e (E split over 2 blocks).
// Wave tile 64p x 64e, 16x16x32 f16, BK=32, 16 K-steps, dbuf'd B in LDS.
// A (W) generated DIRECTLY in MFMA fragment registers: lane (c15,g4) computes
// w[j] for p-row (wrow*64+rt*16+c15), k = g4*8+j. No sW, no A LDS traffic.
// Params per lane = 4x float4 global loads (8 consecutive l's, L1-broadcast).
__global__ __launch_bounds__(256, 3) void field_mfma(
    const float*    __restrict__ cpos,    // (B,P)
    const float2*   __restrict__ params,  // (B,L) {c2*log2e, log2(amp)}
    const _Float16* __restrict__ baset,   // pre-swizzled BASE^T chunks
    float*          __restrict__ out) {   // (B,P,E)

    __shared__ __align__(16) _Float16 sB[2][128 * BK];   // 2 x 8 KB

    const int orig = blockIdx.x;
    const int wg   = (orig & 7) * 256 + (orig >> 3);     // bijective XCD swizzle
    const int b    = wg >> 5;
    const int pt   = (wg >> 1) & 15;
    const int et   = wg & 1;

    const int tid = threadIdx.x, lane = tid & 63, wave = tid >> 6;
    const int c15 = lane & 15, g4 = lane >> 4;
    const int wrow = wave >> 1, wcol = wave & 1;         // 2 x 2 wave grid

    const float invL = 1.0f / (float)(LSEQ - 1);

    // A rows this lane produces/consumes: pb[rt] = pos - (g4*8)*invL
    float pb[4];
#pragma unroll
    for (int rt = 0; rt < 4; ++rt)
        pb[rt] = cpos[b * PDIM + pt * BM + wrow * 64 + rt * 16 + c15]
                 - (float)(g4 * 8) * invL;

    // B frag read offsets (local e row, layout-compatible since 128 % 8 == 0)
    int boff[4];
#pragma unroll
    for (int ct = 0; ct < 4; ++ct)
        boff[ct] = tile_off(wcol * 64 + ct * 16 + c15, g4);

    const float2* prm = params + b * LSEQ;
    // chunk = 8192 elems per (b,t); e-half (et) = contiguous 4096 elems
    const _Float16* bt = baset + (((size_t)b * NT) << 13) + et * 4096;

    // ---- prologue: stage B0,B1 (8 KB each); params(0) ----
#pragma unroll
    for (int buf = 0; buf < 2; ++buf) {
        const _Float16* src = bt + buf * 8192 + wave * 1024 + lane * 8;
        g2lds16(src,       &sB[buf][wave * 1024]);
        g2lds16(src + 512, &sB[buf][wave * 1024 + 512]);
    }

    float4 q0, q1, q2, q3;
    {
        const float4* qp = (const float4*)(prm + g4 * 8);
        q0 = qp[0]; q1 = qp[1]; q2 = qp[2]; q3 = qp[3];
    }
    __syncthreads();

    f32x4 acc[4][4];
#pragma unroll
    for (int i = 0; i < 4; ++i)
#pragma unroll
        for (int j = 0; j < 4; ++j) acc[i][j] = (f32x4)(0.f);

    const float tstep = 32.0f * invL;

    // ---- main loop: one barrier per K-step ----
    for (int t = 0; t < NT; ++t) {
        const int cur = t & 1;

        // genW(t): A-fragments in registers (uses q = params(t))
        f16x8 af[4];
        const float tb = (float)t * tstep;
#pragma unroll
        for (int rt = 0; rt < 4; ++rt) {
            const float pd = pb[rt] - tb;
            float w[8];
#define GW(i, c2, la) { float d = pd - (float)(i) * invL; \
                        w[i] = EXP2F(fmaf(d * d, (c2), (la))); }
            GW(0, q0.x, q0.y) GW(1, q0.z, q0.w)
            GW(2, q1.x, q1.y) GW(3, q1.z, q1.w)
            GW(4, q2.x, q2.y) GW(5, q2.z, q2.w)
            GW(6, q3.x, q3.y) GW(7, q3.z, q3.w)
#undef GW
            ((f16x2*)&af[rt])[0] = pk2(w[0], w[1]);
            ((f16x2*)&af[rt])[1] = pk2(w[2], w[3]);
            ((f16x2*)&af[rt])[2] = pk2(w[4], w[5]);
            ((f16x2*)&af[rt])[3] = pk2(w[6], w[7]);
        }

        if (t < NT - 1) {   // prefetch params(t+1); lands under MFMA + barrier
            const float4* qp = (const float4*)(prm + (t + 1) * BK + g4 * 8);
            q0 = qp[0]; q1 = qp[1]; q2 = qp[2]; q3 = qp[3];
        }

        const _Float16* bb = sB[cur];
        __builtin_amdgcn_s_setprio(1);
#pragma unroll
        for (int ct = 0; ct < 4; ++ct) {
            const f16x8 bf = *(const f16x8*)&bb[boff[ct]];
#pragma unroll
            for (int rt = 0; rt < 4; ++rt)
                acc[rt][ct] = __builtin_amdgcn_mfma_f32_16x16x32_f16(af[rt], bf, acc[rt][ct], 0, 0, 0);
        }
        __builtin_amdgcn_s_setprio(0);

        __syncthreads();   // drains this step's ds_reads + in-flight staging

        if (t < NT - 2) {  // stage B(t+2) into the buffer just consumed
            const _Float16* src = bt + (t + 2) * 8192 + wave * 1024 + lane * 8;
            g2lds16(src,       &sB[cur][wave * 1024]);
            g2lds16(src + 512, &sB[cur][wave * 1024 + 512]);
        }
    }

    // ---- epilogue: C/D 16x16 layout col=lane&15 (e), row=g4*4+reg (p) ----
#pragma unroll
    for (int rt = 0; rt < 4; ++rt)
#pragma unroll
        for (int ct = 0; ct < 4; ++ct) {
            const int e = et * 128 + wcol * 64 + ct * 16 + c15;
#pragma unroll
            for (int reg = 0; reg < 4; ++reg) {
                const int p = pt * BM + wrow * 64 + rt * 16 + g4 * 4 + reg;
                out[((size_t)b * PDIM + p) * EDIM + e] = acc[rt][ct][reg];
            }
        }
}

extern "C" void kernel_launch(void* const* d_in, const int* in_sizes, int n_in,
                              void* d_out, int out_size, void* d_ws, size_t ws_size,
                              hipStream_t stream) {
    const int*   bs   = (const int*)d_in[0];
    const float* cpos = (const float*)d_in[1];
    const float* emb  = (const float*)d_in[2];
    const float* ls   = (const float*)d_in[3];

    const int B = in_sizes[0] / LSEQ;   // 64

    char* ws = (char*)d_ws;
    float2*   params = (float2*)ws;                   // 256 KB
    _Float16* baset  = (_Float16*)(ws + (1u << 18));  // 16 MB

    precompute_all<<<B * NT, 256, 0, stream>>>(bs, ls, emb, params, baset);
    const int nblocks = B * (PDIM / BM) * 2;          // 2048 (E split x2)
    field_mfma<<<nblocks, 256, 0, stream>>>(cpos, params, baset, (float*)d_out);
}